// Round 2
// baseline (238.107 us; speedup 1.0000x reference)
//
#include <hip/hip_runtime.h>
#include <hip/hip_bf16.h>

#define TOKENS   16384
#define DMODEL   2048
#define NEXP     64
#define KW       64      // k-window staged in LDS per iteration
#define NIT      (DMODEL / KW)   // 32
#define TB       64      // tokens per block
#define PAD      68      // padded row length (floats), 16B-aligned, odd multiple of 16B

// out layout (floats): probs[T*2] | indices[T*2] | tokens_per_expert[64] | aux[1]
#define OFF_IDX  (TOKENS * 2)
#define OFF_HIST (TOKENS * 4)
#define OFF_AUX  (TOKENS * 4 + NEXP)

__global__ __launch_bounds__(512) void router_kernel(
    const float* __restrict__ x,      // [T, D]
    const float* __restrict__ gw,     // [E, D]
    float* __restrict__ out,
    float* __restrict__ probsum_g,    // [64] ws accumulator (zeroed)
    float* __restrict__ hist_g)       // [64] ws accumulator (zeroed)
{
    __shared__ float xs[2][TB][PAD];      // 34.8 KB, double-buffered X tile
    __shared__ float ls[TB][PAD];         // 17.4 KB, logits exchange
    __shared__ float psum_s[8][NEXP];     // 2 KB
    __shared__ int   hist_s[NEXP];

    const int tid  = threadIdx.x;
    const int wave = tid >> 6;
    const int lane = tid & 63;
    const int tok0 = blockIdx.x * TB;

    if (tid < NEXP) hist_s[tid] = 0;

    // wave-uniform expert base (pin uniformity for scalar-load selection)
    const int e0 = __builtin_amdgcn_readfirstlane(wave << 3);

    // uniform W row pointers: 8 experts per wave, rows of gate_weight
    const float4* wr[8];
#pragma unroll
    for (int j = 0; j < 8; ++j)
        wr[j] = (const float4*)(gw + (size_t)(e0 + j) * DMODEL);

    float acc[8];
#pragma unroll
    for (int j = 0; j < 8; ++j) acc[j] = 0.f;

    // staging mapping: thread -> (row sr, 8 consecutive floats at sc)
    const int sr = tid >> 3;             // 0..63
    const int sc = (tid & 7) * 8;        // 0,8,...,56
    const float* xrow = x + (size_t)(tok0 + sr) * DMODEL + sc;

    // prologue: stage iter 0, issue loads for iter 1
    float4 ra = *(const float4*)(xrow);
    float4 rb = *(const float4*)(xrow + 4);
    *(float4*)&xs[0][sr][sc]     = ra;
    *(float4*)&xs[0][sr][sc + 4] = rb;
    ra = *(const float4*)(xrow + KW);
    rb = *(const float4*)(xrow + KW + 4);

    for (int it = 0; it < NIT; ++it) {
        const int cur = it & 1;
        if (it + 1 < NIT) {
            // write next tile (regs already in flight), then issue it+2 loads
            *(float4*)&xs[cur ^ 1][sr][sc]     = ra;
            *(float4*)&xs[cur ^ 1][sr][sc + 4] = rb;
            if (it + 2 < NIT) {
                ra = *(const float4*)(xrow + (size_t)(it + 2) * KW);
                rb = *(const float4*)(xrow + (size_t)(it + 2) * KW + 4);
            }
        }
        __syncthreads();   // tile[cur] writes (from prev iter) visible

        const float* xl = &xs[cur][lane][0];
        const int kbase = (it * KW) >> 2;   // float4 index into W rows
#pragma unroll 4
        for (int kk = 0; kk < KW / 4; ++kk) {
            float4 xv = *(const float4*)(xl + kk * 4);
#pragma unroll
            for (int j = 0; j < 8; ++j) {
                float4 wv = wr[j][kbase + kk];   // wave-uniform -> s_load
                acc[j] = fmaf(xv.x, wv.x, acc[j]);
                acc[j] = fmaf(xv.y, wv.y, acc[j]);
                acc[j] = fmaf(xv.z, wv.z, acc[j]);
                acc[j] = fmaf(xv.w, wv.w, acc[j]);
            }
        }
        __syncthreads();   // all waves done reading tile[cur] before overwrite
    }

    // ---- exchange logits: ls[token][expert] ----
    *(float4*)&ls[lane][e0]     = make_float4(acc[0], acc[1], acc[2], acc[3]);
    *(float4*)&ls[lane][e0 + 4] = make_float4(acc[4], acc[5], acc[6], acc[7]);
    __syncthreads();

    // ---- epilogue: 8 waves x 8 tokens, lane = expert ----
    float local_psum = 0.f;
#pragma unroll
    for (int t = 0; t < 8; ++t) {
        const int tl = wave * 8 + t;
        float v = ls[tl][lane];
        float m = v;
#pragma unroll
        for (int off = 32; off; off >>= 1) m = fmaxf(m, __shfl_xor(m, off));
        float ex = __expf(v - m);
        float S = ex;
#pragma unroll
        for (int off = 32; off; off >>= 1) S += __shfl_xor(S, off);
        local_psum += ex / S;

        float bv = v; int bi = lane;
#pragma unroll
        for (int off = 32; off; off >>= 1) {
            float ov = __shfl_xor(bv, off);
            int   oi = __shfl_xor(bi, off);
            if (ov > bv || (ov == bv && oi < bi)) { bv = ov; bi = oi; }
        }
        float v1 = bv; int i1 = bi;
        float bv2 = (lane == i1) ? -3.4e38f : v; int bi2 = lane;
#pragma unroll
        for (int off = 32; off; off >>= 1) {
            float ov = __shfl_xor(bv2, off);
            int   oi = __shfl_xor(bi2, off);
            if (ov > bv2 || (ov == bv2 && oi < bi2)) { bv2 = ov; bi2 = oi; }
        }
        float v2 = bv2; int i2 = bi2;

        if (lane == 0) {
            float e1 = __expf(v1 - m);
            float e2 = __expf(v2 - m);
            float inv = 1.f / (e1 + e2);
            int tok = tok0 + tl;
            out[tok * 2 + 0] = e1 * inv;
            out[tok * 2 + 1] = e2 * inv;
            out[OFF_IDX + tok * 2 + 0] = (float)i1;
            out[OFF_IDX + tok * 2 + 1] = (float)i2;
            atomicAdd(&hist_s[i1], 1);
            atomicAdd(&hist_s[i2], 1);
        }
    }

    psum_s[wave][lane] = local_psum;
    __syncthreads();
    if (wave == 0) {
        float s = 0.f;
#pragma unroll
        for (int i = 0; i < 8; ++i) s += psum_s[i][lane];
        atomicAdd(&probsum_g[lane], s);
        atomicAdd(&hist_g[lane], (float)hist_s[lane]);
    }
}

__global__ void finalize_kernel(const float* __restrict__ probsum_g,
                                const float* __restrict__ hist_g,
                                float* __restrict__ out)
{
    int e = threadIdx.x;  // 64 threads
    float tpe = hist_g[e];
    out[OFF_HIST + e] = tpe;
    const float invT = 1.f / (float)TOKENS;
    float term = (tpe * invT) * (probsum_g[e] * invT);
#pragma unroll
    for (int off = 32; off; off >>= 1) term += __shfl_xor(term, off);
    if (e == 0) out[OFF_AUX] = term * (float)NEXP;
}

extern "C" void kernel_launch(void* const* d_in, const int* in_sizes, int n_in,
                              void* d_out, int out_size, void* d_ws, size_t ws_size,
                              hipStream_t stream) {
    const float* x  = (const float*)d_in[0];
    const float* gw = (const float*)d_in[1];
    float* out = (float*)d_out;
    float* ws  = (float*)d_ws;   // probsum[64] | hist[64]

    hipMemsetAsync(d_ws, 0, 128 * sizeof(float), stream);

    dim3 grid(TOKENS / TB);      // 256 blocks, 512 threads = 8 waves
    router_kernel<<<grid, 512, 0, stream>>>(x, gw, out, ws, ws + NEXP);
    finalize_kernel<<<1, 64, 0, stream>>>(ws, ws + NEXP, out);
}